// Round 9
// baseline (817.210 us; speedup 1.0000x reference)
//
#include <hip/hip_runtime.h>
#include <hip/hip_bf16.h>
#include <math.h>

// Problem constants
#define DIN   128
#define DOUTC 128
#define HH    8
#define DHH   16
#define DGG   64
#define NC2   352      // padded cols: 128 f0 | 128 f1 | 64 zj | 8 fg0 | 8 fg2 | 16 pad
#define PH    176      // cols per LDS phase
#define PT    11       // tiles per phase
#define BSHIFT 7       // 128 rows per bucket
#define CAP   6144     // max edges per bucket
#define HB    64       // bhist blocks (private slices)

typedef __attribute__((ext_vector_type(8))) short short8v;   // 8 bf16 (4 VGPRs)
typedef __attribute__((ext_vector_type(4))) float float4v;   // 4 fp32 acc

// ---------------- setup: cvt_feat | prep2 | bhist64 (block-role split) ----------------
__global__ __launch_bounds__(256) void setup_kernel(
    const float* __restrict__ feat, const float* __restrict__ W, const float* __restrict__ b,
    const float* __restrict__ Wg, const float* __restrict__ Wpg, const int* __restrict__ row,
    __hip_bfloat16* __restrict__ featb, __hip_bfloat16* __restrict__ Btb, float* __restrict__ biasv,
    int* __restrict__ gHistP, int total8, int cvtB, int prepB, int E, int EH) {
    int bid = blockIdx.x, tid = threadIdx.x;
    if (bid < cvtB) {
        int i = bid * 256 + tid;
        if (i < total8) {
            const float4* p = reinterpret_cast<const float4*>(feat) + 2 * (size_t)i;
            float4 x = p[0], y = p[1];
            union { __hip_bfloat16 h[8]; short8v v; } pk;
            pk.h[0] = __float2bfloat16(x.x); pk.h[1] = __float2bfloat16(x.y);
            pk.h[2] = __float2bfloat16(x.z); pk.h[3] = __float2bfloat16(x.w);
            pk.h[4] = __float2bfloat16(y.x); pk.h[5] = __float2bfloat16(y.y);
            pk.h[6] = __float2bfloat16(y.z); pk.h[7] = __float2bfloat16(y.w);
            reinterpret_cast<short8v*>(featb)[i] = pk.v;
        }
    } else if (bid < cvtB + prepB) {
        int idx = (bid - cvtB) * 256 + tid;
        if (idx < NC2 * DIN) {
            int col = idx >> 7;   // 0..351
            int k   = idx & 127;  // input dim
            float v = 0.f;
            if (col < 256) {
                int o = col >> 7, jj = col & 127, h = jj >> 4, kd = jj & 15;
                v = W[((o * HH + h) * DIN + k) * DHH + kd];
            } else if (col < 320) {
                v = Wpg[k * DGG + (col - 256)];
            } else if (col < 328) {
                v = Wg[k * HH + (col - 320)];            // fg0: Wg rows 0..127
            } else if (col < 336) {
                v = Wg[(192 + k) * HH + (col - 328)];    // fg2: Wg rows 192..319
            }
            // LDS-swizzle baked in: unit u = (k>>3) ^ (col&7)
            int u = (k >> 3) ^ (col & 7);
            Btb[col * DIN + u * 8 + (k & 7)] = __float2bfloat16(v);
        }
        if (idx < NC2) {
            float bv = 0.f;
            if (idx < 256) { int o = idx >> 7, jj = idx & 127; bv = b[(o * HH + (jj >> 4)) * DHH + (jj & 15)]; }
            biasv[idx] = bv;
        }
    } else {
        // bhist: private slice per block, no global atomics, no pre-zero needed
        __shared__ int hist[512];
        int hb = bid - cvtB - prepB;          // 0..HB-1
        hist[tid] = 0; hist[tid + 256] = 0;
        __syncthreads();
        int e0 = hb * EH, e1 = e0 + EH; if (e1 > E) e1 = E;
        for (int e = e0 + tid; e < e1; e += 256) atomicAdd(&hist[row[e] >> BSHIFT], 1);
        __syncthreads();
        gHistP[hb * 512 + tid] = hist[tid];
        gHistP[hb * 512 + tid + 256] = hist[tid + 256];
    }
}

// ---------------- dense MFMA v3: BM=64, 4 waves x 16 rows, LDS-shared B^T ----------------
__global__ __launch_bounds__(256) void dense_mfma(
    const __hip_bfloat16* __restrict__ featb, const __hip_bfloat16* __restrict__ Btb,
    const float* __restrict__ biasv,
    float* __restrict__ f0, __hip_bfloat16* __restrict__ f1b, __hip_bfloat16* __restrict__ zjb,
    float* __restrict__ fg0, float* __restrict__ nodedat, int N) {
    __shared__ __align__(16) __hip_bfloat16 Bs[PH * DIN];   // 45056 B -> 3 blocks/CU
    int t   = threadIdx.x;
    int wid = t >> 6, l = t & 63;
    int r0  = blockIdx.x * 64 + wid * 16;
    int lr  = l & 15;        // fragment row/col index
    int lk  = l >> 4;        // k-group (0..3)

    // A fragments: a[kk] = featb[row = r0+lr][k = kk*32 + lk*8 .. +8]
    short8v a[4];
    {
        int node = r0 + lr;
        if (node >= N) node = N - 1;           // clamp loads; stores guarded below
        const short8v* ap = reinterpret_cast<const short8v*>(&featb[(size_t)node * DIN + lk * 8]);
        #pragma unroll
        for (int kk = 0; kk < 4; ++kk) a[kk] = ap[kk * 4];
    }

    #pragma unroll
    for (int p = 0; p < 2; ++p) {
        __syncthreads();   // prior phase's ds_reads done before overwrite
        {
            const short8v* src = reinterpret_cast<const short8v*>(Btb + (size_t)p * PH * DIN);
            short8v* dst = reinterpret_cast<short8v*>(Bs);
            #pragma unroll
            for (int it = 0; it < 11; ++it) dst[it * 256 + t] = src[it * 256 + t];
        }
        __syncthreads();

        float4v acc[PT];
        #pragma unroll
        for (int n = 0; n < PT; ++n) acc[n] = (float4v)0.f;

        #pragma unroll
        for (int n = 0; n < PT; ++n) {
            int coll = n * 16 + lr;
            #pragma unroll
            for (int kk = 0; kk < 4; ++kk) {
                int u = (kk * 4 + lk) ^ (lr & 7);
                short8v bv = *reinterpret_cast<const short8v*>(&Bs[coll * DIN + u * 8]);
                acc[n] = __builtin_amdgcn_mfma_f32_16x16x32_bf16(a[kk], bv, acc[n], 0, 0, 0);
            }
        }

        // Epilogue: C/D layout col=lane&15 (=lr), row=(lane>>4)*4+reg (= lk*4+rg)
        #pragma unroll
        for (int rg = 0; rg < 4; ++rg) {
            int node = r0 + lk * 4 + rg;
            if (node < N) {
                #pragma unroll
                for (int n = 0; n < PT; ++n) {
                    int col = p * PH + n * 16 + lr;
                    float v = acc[n][rg] + biasv[col];
                    if (col < 128) {
                        v = v > 0.f ? v : 0.f;
                        f0[(size_t)node * DOUTC + col] = v;
                    } else if (col < 256) {
                        v = v > 0.f ? v : 0.f;
                        f1b[(size_t)node * DOUTC + (col - 128)] = __float2bfloat16(v);
                    } else if (col < 320) {
                        zjb[(size_t)node * DGG + (col - 256)] = __float2bfloat16(v);
                    } else if (col < 328) {
                        fg0[node * HH + (col - 320)] = v;
                    } else if (col < 336) {
                        nodedat[(size_t)node * 16 + 8 + (col - 328)] = v;  // fg2 half
                    }
                }
            }
        }
    }
}

// ---------------- mid: attn dots | bscan (block-role split, 512 threads) ----------------
__global__ __launch_bounds__(512) void mid_kernel(
    const float* __restrict__ f0, const __hip_bfloat16* __restrict__ f1b,
    const float* __restrict__ att, float* __restrict__ a_self, float* __restrict__ nodedat,
    const int* __restrict__ gHistP, int* __restrict__ gHist, int* __restrict__ gBase,
    int* __restrict__ gCursor, int N, int attnB) {
    int bid = blockIdx.x, tid = threadIdx.x;
    if (bid < attnB) {
        int g = bid * 512 + tid;
        if (g >= N * 16) return;
        int node = g >> 4, u = g & 15, h = u >> 1;
        float s = 0.f;
        if ((u & 1) == 0) {
            const float4* p  = reinterpret_cast<const float4*>(&f0[(size_t)node * DOUTC + h * DHH]);
            const float*  av = &att[h * 32];
            #pragma unroll
            for (int q = 0; q < 4; ++q) {
                float4 x = p[q];
                s = fmaf(x.x, av[q * 4 + 0], fmaf(x.y, av[q * 4 + 1],
                    fmaf(x.z, av[q * 4 + 2], fmaf(x.w, av[q * 4 + 3], s))));
            }
            s = (s >= 0.f) ? s : 0.2f * s;
            a_self[node * HH + h] = s;
        } else {
            const short8v* p = reinterpret_cast<const short8v*>(&f1b[(size_t)node * DOUTC + h * DHH]);
            const float*  av = &att[h * 32 + DHH];
            union { short8v v; __hip_bfloat16 hh[8]; } pk0, pk1;
            pk0.v = p[0]; pk1.v = p[1];
            #pragma unroll
            for (int q = 0; q < 8; ++q) s = fmaf(__bfloat162float(pk0.hh[q]), av[q], s);
            #pragma unroll
            for (int q = 0; q < 8; ++q) s = fmaf(__bfloat162float(pk1.hh[q]), av[8 + q], s);
            s = (s >= 0.f) ? s : 0.2f * s;
            nodedat[(size_t)node * 16 + h] = s;   // a_neigh half
        }
    } else {
        // bscan: sum HB private slices, exclusive-scan, write gHist/gBase/gCursor
        __shared__ int s[512];
        int v = 0;
        #pragma unroll
        for (int s8 = 0; s8 < HB; ++s8) v += gHistP[s8 * 512 + tid];
        gHist[tid] = v;
        s[tid] = v; __syncthreads();
        for (int off = 1; off < 512; off <<= 1) {
            int add = (tid >= off) ? s[tid - off] : 0;
            __syncthreads();
            s[tid] += add;
            __syncthreads();
        }
        int excl = s[tid] - v;
        gBase[tid] = excl;
        gCursor[tid] = excl;
    }
}

// ---------------- bscatter: edges -> bucket regions ----------------
#define EPB   4096
__global__ __launch_bounds__(256) void bscatter(const int* __restrict__ row, const int* __restrict__ col,
                                                const float* __restrict__ val, int* __restrict__ gCursor,
                                                int2* __restrict__ ebuf, int E) {
    __shared__ int hist[512], base[512], rank[512];
    int tid = threadIdx.x;
    hist[tid] = 0; hist[tid + 256] = 0;
    __syncthreads();
    int e0 = blockIdx.x * EPB;
    #pragma unroll
    for (int k = 0; k < 16; ++k) {
        int e = e0 + k * 256 + tid;
        if (e < E) atomicAdd(&hist[row[e] >> BSHIFT], 1);
    }
    __syncthreads();
    if (hist[tid])       base[tid] = atomicAdd(&gCursor[tid], hist[tid]);
    if (hist[tid + 256]) base[tid + 256] = atomicAdd(&gCursor[tid + 256], hist[tid + 256]);
    rank[tid] = 0; rank[tid + 256] = 0;
    __syncthreads();
    #pragma unroll
    for (int k = 0; k < 16; ++k) {
        int e = e0 + k * 256 + tid;
        if (e < E) {
            int r = row[e];
            int bk = r >> BSHIFT;
            int loc = atomicAdd(&rank[bk], 1);
            int2 pk;
            pk.x = col[e] | ((r & 127) << 16);   // col fits 16 bits (N < 65536)
            pk.y = __float_as_int(val[e]);
            ebuf[base[bk] + loc] = pk;
        }
    }
}

// ---------------- bsort: per-bucket counting sort -> final edges + rowptr ----------------
__global__ __launch_bounds__(256) void bsort(const int2* __restrict__ ebuf, const int* __restrict__ gHist,
                                             const int* __restrict__ gBase, int2* __restrict__ efin,
                                             int* __restrict__ rowptr, int N) {
    __shared__ int2 ent[CAP];
    __shared__ int h0[128], sc[128], rk[128];
    int b = blockIdx.x, tid = threadIdx.x;
    int cnt = gHist[b]; if (cnt > CAP) cnt = CAP;
    int base = gBase[b];
    if (tid < 128) h0[tid] = 0;
    __syncthreads();
    for (int i = tid; i < cnt; i += 256) {
        int2 e = ebuf[base + i];
        ent[i] = e;
        atomicAdd(&h0[(e.x >> 16) & 127], 1);
    }
    __syncthreads();
    if (tid < 128) sc[tid] = h0[tid];
    __syncthreads();
    for (int off = 1; off < 128; off <<= 1) {
        int add = (tid < 128 && tid >= off) ? sc[tid - off] : 0;
        __syncthreads();
        if (tid < 128) sc[tid] += add;
        __syncthreads();
    }
    if (tid < 128) {
        int excl = sc[tid] - h0[tid];
        rk[tid] = excl;
        int grow = b * 128 + tid;
        if (grow <= N) rowptr[grow] = base + excl;   // rowptr[N] = E via last bucket
    }
    __syncthreads();
    for (int i = tid; i < cnt; i += 256) {
        int2 e = ent[i];
        int dst = base + atomicAdd(&rk[(e.x >> 16) & 127], 1);
        efin[dst] = e;
    }
}

// ---------------- edge aggregation + gate + fused dual-norm (persistent blocks) ----------------
#define UN 8
__global__ __launch_bounds__(128) void edge_kernel(
    const int* __restrict__ rowptr, const int2* __restrict__ ef,
    const __hip_bfloat16* __restrict__ f1b, const __hip_bfloat16* __restrict__ zjb,
    const float* __restrict__ a_self, const float* __restrict__ nodedat,
    const float* __restrict__ fg0, const float* __restrict__ Wg,
    const float* __restrict__ f0, const float* __restrict__ scale, const float* __restrict__ offset,
    float* __restrict__ out, int N, int gstride) {
    int t = threadIdx.x;
    int h = t >> 3;
    int j = t - 64;

    __shared__ float lds_z[64];
    __shared__ float lds_n8[8];
    __shared__ float lds_gate[8];

    for (int r = blockIdx.x; r < N; r += gstride) {
        int start = rowptr[r], end = rowptr[r + 1];

        float accA0 = 0.f, accA1 = 0.f, accZ = -INFINITY, accN8 = 0.f;
        float asr = 0.f;
        if (t < 64) asr = a_self[r * HH + h];

        int i = start;
        for (; i + UN <= end; i += UN) {
            int   c[UN]; float v[UN];
            #pragma unroll
            for (int u = 0; u < UN; ++u) {
                int2 eu = ef[i + u];
                c[u] = eu.x & 0xFFFF;
                v[u] = __int_as_float(eu.y);
            }
            if (t < 64) {
                float an[UN];
                #pragma unroll
                for (int u = 0; u < UN; ++u) an[u] = nodedat[(size_t)c[u] * 16 + h];
                __hip_bfloat162 f2[UN];
                #pragma unroll
                for (int u = 0; u < UN; ++u)
                    f2[u] = *reinterpret_cast<const __hip_bfloat162*>(&f1b[(size_t)c[u] * DOUTC + 2 * t]);
                #pragma unroll
                for (int u = 0; u < UN; ++u) {
                    float w = (asr + an[u]) * v[u];
                    accA0 = fmaf(w, __bfloat162float(f2[u].x), accA0);
                    accA1 = fmaf(w, __bfloat162float(f2[u].y), accA1);
                }
            } else {
                float z[UN];
                #pragma unroll
                for (int u = 0; u < UN; ++u) z[u] = __bfloat162float(zjb[(size_t)c[u] * DGG + j]);
                #pragma unroll
                for (int u = 0; u < UN; ++u) accZ = fmaxf(accZ, z[u]);
                if (j < 8) {
                    float g2[UN];
                    #pragma unroll
                    for (int u = 0; u < UN; ++u) g2[u] = nodedat[(size_t)c[u] * 16 + 8 + j];
                    #pragma unroll
                    for (int u = 0; u < UN; ++u) accN8 = fmaf(v[u], g2[u], accN8);
                }
            }
        }
        for (; i < end; ++i) {
            int2 eu = ef[i];
            int   c = eu.x & 0xFFFF;
            float v = __int_as_float(eu.y);
            if (t < 64) {
                float w = (asr + nodedat[(size_t)c * 16 + h]) * v;
                __hip_bfloat162 f2 = *reinterpret_cast<const __hip_bfloat162*>(&f1b[(size_t)c * DOUTC + 2 * t]);
                accA0 = fmaf(w, __bfloat162float(f2.x), accA0);
                accA1 = fmaf(w, __bfloat162float(f2.y), accA1);
            } else {
                accZ = fmaxf(accZ, __bfloat162float(zjb[(size_t)c * DGG + j]));
                if (j < 8) accN8 = fmaf(v, nodedat[(size_t)c * 16 + 8 + j], accN8);
            }
        }

        if (t >= 64) {
            lds_z[j] = (end > start) ? accZ : 0.f;  // isolated node -> 0
            if (j < 8) lds_n8[j] = accN8;
        }
        __syncthreads();

        if (t < 8) {   // gate[h] = fg0 + zmax . Wg[128:192] + nm8
            float g = fg0[r * HH + t] + lds_n8[t];
            #pragma unroll
            for (int k = 0; k < 64; ++k) g = fmaf(lds_z[k], Wg[(128 + k) * HH + t], g);
            lds_gate[t] = g;
        }
        __syncthreads();

        if (t < 64) {
            float gh  = lds_gate[h];
            float h1x = accA0 * gh, h1y = accA1 * gh;
            float2 f0v = *reinterpret_cast<const float2*>(&f0[r * DOUTC + 2 * t]);
            float s0  = f0v.x + f0v.y;
            float s0q = f0v.x * f0v.x + f0v.y * f0v.y;
            float s1  = h1x + h1y;
            float s1q = h1x * h1x + h1y * h1y;
            #pragma unroll
            for (int off = 32; off > 0; off >>= 1) {
                s0  += __shfl_xor(s0,  off);
                s0q += __shfl_xor(s0q, off);
                s1  += __shfl_xor(s1,  off);
                s1q += __shfl_xor(s1q, off);
            }
            float mu0  = s0 * (1.f / 128.f), mu1 = s1 * (1.f / 128.f);
            float rs0  = rsqrtf(s0q * (1.f / 128.f) - mu0 * mu0 + 1e-9f);
            float rs1  = rsqrtf(s1q * (1.f / 128.f) - mu1 * mu1 + 1e-9f);
            float2 sc0 = *reinterpret_cast<const float2*>(&scale[2 * t]);
            float2 sc1 = *reinterpret_cast<const float2*>(&scale[128 + 2 * t]);
            float2 of0 = *reinterpret_cast<const float2*>(&offset[2 * t]);
            float2 of1 = *reinterpret_cast<const float2*>(&offset[128 + 2 * t]);
            float2 o2;
            o2.x = (f0v.x - mu0) * sc0.x * rs0 + of0.x + (h1x - mu1) * sc1.x * rs1 + of1.x;
            o2.y = (f0v.y - mu0) * sc0.y * rs0 + of0.y + (h1y - mu1) * sc1.y * rs1 + of1.y;
            *reinterpret_cast<float2*>(&out[r * DOUTC + 2 * t]) = o2;
        }
    }
}

// ---------------- launch ----------------
extern "C" void kernel_launch(void* const* d_in, const int* in_sizes, int n_in,
                              void* d_out, int out_size, void* d_ws, size_t ws_size,
                              hipStream_t stream) {
    const int*   row  = (const int*)  d_in[0];
    const int*   col  = (const int*)  d_in[1];
    const float* val  = (const float*)d_in[2];
    const float* feat = (const float*)d_in[3];
    const float* W    = (const float*)d_in[4];
    const float* b    = (const float*)d_in[5];
    const float* att  = (const float*)d_in[6];
    const float* offs = (const float*)d_in[7];
    const float* scal = (const float*)d_in[8];
    const float* Wg   = (const float*)d_in[9];
    const float* Wpg  = (const float*)d_in[10];
    float* out = (float*)d_out;

    const int E = in_sizes[0];
    const int N = in_sizes[3] / DIN;
    const int NBUCK = (N + 127) >> BSHIFT;       // 391 for N=50000
    const int NEBLK = (E + EPB - 1) / EPB;       // 391 for E=1.6M

    char* ws = (char*)d_ws;
    size_t off = 0;
    auto alloc = [&](size_t bytes) { size_t o = off; off = (off + bytes + 255) & ~(size_t)255; return o; };

    __hip_bfloat16* featb = (__hip_bfloat16*)(ws + alloc((size_t)N * DIN * 2));
    __hip_bfloat16* Btb   = (__hip_bfloat16*)(ws + alloc((size_t)NC2 * DIN * 2));
    float* biasv   = (float*)(ws + alloc(NC2 * 4));
    float* f0      = (float*)(ws + alloc((size_t)N * DOUTC * 4));
    __hip_bfloat16* f1b = (__hip_bfloat16*)(ws + alloc((size_t)N * DOUTC * 2));
    __hip_bfloat16* zjb = (__hip_bfloat16*)(ws + alloc((size_t)N * DGG * 2));
    float* a_self  = (float*)(ws + alloc((size_t)N * HH * 4));
    float* nodedat = (float*)(ws + alloc((size_t)N * 16 * 4));   // [a_neigh(8) | fg2(8)] per node
    float* fg0     = (float*)(ws + alloc((size_t)N * HH * 4));
    int*   rowptr  = (int*)  (ws + alloc((size_t)(N + 1) * 4));
    int*   gHistP  = (int*)  (ws + alloc((size_t)HB * 512 * 4));
    int*   gHist   = (int*)  (ws + alloc(512 * 4));
    int*   gBase   = (int*)  (ws + alloc(512 * 4));
    int*   gCursor = (int*)  (ws + alloc(512 * 4));
    int2*  ebuf    = (int2*) (ws + alloc((size_t)E * 8));
    int2*  efin    = (int2*) (ws + alloc((size_t)E * 8));

    // 1. setup: feat->bf16 | pack swizzled B^T | bucket histogram slices
    const int total8 = N * DIN / 8;
    const int cvtB = (total8 + 255) / 256;
    const int prepB = (NC2 * DIN + 255) / 256;
    const int EH = (E + HB - 1) / HB;
    setup_kernel<<<cvtB + prepB + HB, 256, 0, stream>>>(
        feat, W, b, Wg, Wpg, row, featb, Btb, biasv, gHistP, total8, cvtB, prepB, E, EH);
    // 2. dense MFMA GEMM v3 (BM=64, 12 waves/CU)
    dense_mfma<<<(N + 63) / 64, 256, 0, stream>>>(featb, Btb, biasv, f0, f1b, zjb, fg0, nodedat, N);
    // 3. mid: attention scalars | bucket scan
    const int attnB = (N * 16 + 511) / 512;
    mid_kernel<<<attnB + 1, 512, 0, stream>>>(f0, f1b, att, a_self, nodedat,
                                              gHistP, gHist, gBase, gCursor, N, attnB);
    // 4. bucketed counting sort
    bscatter<<<NEBLK, 256, 0, stream>>>(row, col, val, gCursor, ebuf, E);
    bsort<<<NBUCK, 256, 0, stream>>>(ebuf, gHist, gBase, efin, rowptr, N);
    // 5. per-node aggregation (persistent blocks, 8 nodes each)
    const int ge = (N + 7) / 8;
    edge_kernel<<<ge, 128, 0, stream>>>(rowptr, efin, f1b, zjb, a_self, nodedat,
                                        fg0, Wg, f0, scal, offs, out, N, ge);
}

// Round 10
// 341.771 us; speedup vs baseline: 2.3911x; 2.3911x over previous
//
#include <hip/hip_runtime.h>
#include <hip/hip_bf16.h>
#include <math.h>

// Problem constants
#define DIN   128
#define DOUTC 128
#define HH    8
#define DHH   16
#define DGG   64
#define NC2   352      // padded cols: 128 f0 | 128 f1 | 64 zj | 8 fg0 | 8 fg2 | 16 pad
#define PH    176      // cols per LDS phase
#define PT    11       // tiles per phase
#define BSHIFT 7       // 128 rows per bucket
#define CAP   6144     // max edges per bucket
#define HB    64       // bhist blocks (private slices)
#define EPB   4096     // edges per block in bucket passes

typedef __attribute__((ext_vector_type(8))) short short8v;   // 8 bf16 (4 VGPRs)
typedef __attribute__((ext_vector_type(4))) float float4v;   // 4 fp32 acc

// ---------------- setup: cvt_feat | prep2 | bhist64 (block-role split) ----------------
__global__ __launch_bounds__(256) void setup_kernel(
    const float* __restrict__ feat, const float* __restrict__ W, const float* __restrict__ b,
    const float* __restrict__ Wg, const float* __restrict__ Wpg, const int* __restrict__ row,
    __hip_bfloat16* __restrict__ featb, __hip_bfloat16* __restrict__ Btb, float* __restrict__ biasv,
    int* __restrict__ gHistP, int total8, int cvtB, int prepB, int E, int EH) {
    int bid = blockIdx.x, tid = threadIdx.x;
    if (bid < cvtB) {
        int i = bid * 256 + tid;
        if (i < total8) {
            const float4* p = reinterpret_cast<const float4*>(feat) + 2 * (size_t)i;
            float4 x = p[0], y = p[1];
            union { __hip_bfloat16 h[8]; short8v v; } pk;
            pk.h[0] = __float2bfloat16(x.x); pk.h[1] = __float2bfloat16(x.y);
            pk.h[2] = __float2bfloat16(x.z); pk.h[3] = __float2bfloat16(x.w);
            pk.h[4] = __float2bfloat16(y.x); pk.h[5] = __float2bfloat16(y.y);
            pk.h[6] = __float2bfloat16(y.z); pk.h[7] = __float2bfloat16(y.w);
            reinterpret_cast<short8v*>(featb)[i] = pk.v;
        }
    } else if (bid < cvtB + prepB) {
        int idx = (bid - cvtB) * 256 + tid;
        if (idx < NC2 * DIN) {
            int col = idx >> 7;   // 0..351
            int k   = idx & 127;  // input dim
            float v = 0.f;
            if (col < 256) {
                int o = col >> 7, jj = col & 127, h = jj >> 4, kd = jj & 15;
                v = W[((o * HH + h) * DIN + k) * DHH + kd];
            } else if (col < 320) {
                v = Wpg[k * DGG + (col - 256)];
            } else if (col < 328) {
                v = Wg[k * HH + (col - 320)];            // fg0: Wg rows 0..127
            } else if (col < 336) {
                v = Wg[(192 + k) * HH + (col - 328)];    // fg2: Wg rows 192..319
            }
            // LDS-swizzle baked in: unit u = (k>>3) ^ (col&7)
            int u = (k >> 3) ^ (col & 7);
            Btb[col * DIN + u * 8 + (k & 7)] = __float2bfloat16(v);
        }
        if (idx < NC2) {
            float bv = 0.f;
            if (idx < 256) { int o = idx >> 7, jj = idx & 127; bv = b[(o * HH + (jj >> 4)) * DHH + (jj & 15)]; }
            biasv[idx] = bv;
        }
    } else {
        // bhist: private slice per block, no global atomics, no pre-zero needed
        __shared__ int hist[512];
        int hb = bid - cvtB - prepB;          // 0..HB-1
        hist[tid] = 0; hist[tid + 256] = 0;
        __syncthreads();
        int e0 = hb * EH, e1 = e0 + EH; if (e1 > E) e1 = E;
        for (int e = e0 + tid; e < e1; e += 256) atomicAdd(&hist[row[e] >> BSHIFT], 1);
        __syncthreads();
        gHistP[hb * 512 + tid] = hist[tid];
        gHistP[hb * 512 + tid + 256] = hist[tid + 256];
    }
}

// ---------------- dense MFMA v2 + explicit (256,1): no VGPR cap -> no spill ----------------
// Block = 4 waves x 32 rows = 128 rows, LDS-shared swizzled B^T in 2 phases of 176 cols.
__global__ __launch_bounds__(256, 1) void dense_mfma(
    const __hip_bfloat16* __restrict__ featb, const __hip_bfloat16* __restrict__ Btb,
    const float* __restrict__ biasv,
    float* __restrict__ f0, __hip_bfloat16* __restrict__ f1b, __hip_bfloat16* __restrict__ zjb,
    float* __restrict__ fg0, float* __restrict__ nodedat, int N) {
    __shared__ __align__(16) __hip_bfloat16 Bs[PH * DIN];   // 45056 B -> 3 blocks/CU
    int t   = threadIdx.x;
    int wid = t >> 6, l = t & 63;
    int r0  = blockIdx.x * 128 + wid * 32;
    int lr  = l & 15;        // fragment row/col index
    int lk  = l >> 4;        // k-group (0..3)

    // A fragments: a[rt][kk] = featb[row = r0+rt*16+lr][k = kk*32 + lk*8 .. +8]
    short8v a[2][4];
    #pragma unroll
    for (int rt = 0; rt < 2; ++rt) {
        int node = r0 + rt * 16 + lr;
        if (node >= N) node = N - 1;           // clamp loads; stores guarded below
        const short8v* ap = reinterpret_cast<const short8v*>(&featb[(size_t)node * DIN + lk * 8]);
        #pragma unroll
        for (int kk = 0; kk < 4; ++kk) a[rt][kk] = ap[kk * 4];
    }

    #pragma unroll
    for (int p = 0; p < 2; ++p) {
        __syncthreads();   // prior phase's ds_reads done before overwrite
        {
            const short8v* src = reinterpret_cast<const short8v*>(Btb + (size_t)p * PH * DIN);
            short8v* dst = reinterpret_cast<short8v*>(Bs);
            #pragma unroll
            for (int it = 0; it < 11; ++it) dst[it * 256 + t] = src[it * 256 + t];
        }
        __syncthreads();

        float4v acc[2][PT];
        #pragma unroll
        for (int rt = 0; rt < 2; ++rt)
            #pragma unroll
            for (int n = 0; n < PT; ++n) acc[rt][n] = (float4v)0.f;

        #pragma unroll
        for (int n = 0; n < PT; ++n) {
            int coll = n * 16 + lr;
            #pragma unroll
            for (int kk = 0; kk < 4; ++kk) {
                int u = (kk * 4 + lk) ^ (lr & 7);
                short8v bv = *reinterpret_cast<const short8v*>(&Bs[coll * DIN + u * 8]);
                acc[0][n] = __builtin_amdgcn_mfma_f32_16x16x32_bf16(a[0][kk], bv, acc[0][n], 0, 0, 0);
                acc[1][n] = __builtin_amdgcn_mfma_f32_16x16x32_bf16(a[1][kk], bv, acc[1][n], 0, 0, 0);
            }
        }

        // Epilogue: C/D layout col=lane&15 (=lr), row=(lane>>4)*4+reg (= lk*4+rg)
        #pragma unroll
        for (int rt = 0; rt < 2; ++rt) {
            #pragma unroll
            for (int rg = 0; rg < 4; ++rg) {
                int node = r0 + rt * 16 + lk * 4 + rg;
                if (node < N) {
                    #pragma unroll
                    for (int n = 0; n < PT; ++n) {
                        int col = p * PH + n * 16 + lr;
                        float v = acc[rt][n][rg] + biasv[col];
                        if (col < 128) {
                            v = v > 0.f ? v : 0.f;
                            f0[(size_t)node * DOUTC + col] = v;
                        } else if (col < 256) {
                            v = v > 0.f ? v : 0.f;
                            f1b[(size_t)node * DOUTC + (col - 128)] = __float2bfloat16(v);
                        } else if (col < 320) {
                            zjb[(size_t)node * DGG + (col - 256)] = __float2bfloat16(v);
                        } else if (col < 328) {
                            fg0[node * HH + (col - 320)] = v;
                        } else if (col < 336) {
                            nodedat[(size_t)node * 16 + 8 + (col - 328)] = v;  // fg2 half
                        }
                    }
                }
            }
        }
    }
}

// ---------------- mid: attn dots | bscan (block-role split, 512 threads) ----------------
__global__ __launch_bounds__(512) void mid_kernel(
    const float* __restrict__ f0, const __hip_bfloat16* __restrict__ f1b,
    const float* __restrict__ att, float* __restrict__ a_self, float* __restrict__ nodedat,
    const int* __restrict__ gHistP, int* __restrict__ gHist, int* __restrict__ gBase,
    int* __restrict__ gCursor, int N, int attnB) {
    int bid = blockIdx.x, tid = threadIdx.x;
    if (bid < attnB) {
        int g = bid * 512 + tid;
        if (g >= N * 16) return;
        int node = g >> 4, u = g & 15, h = u >> 1;
        float s = 0.f;
        if ((u & 1) == 0) {
            const float4* p  = reinterpret_cast<const float4*>(&f0[(size_t)node * DOUTC + h * DHH]);
            const float*  av = &att[h * 32];
            #pragma unroll
            for (int q = 0; q < 4; ++q) {
                float4 x = p[q];
                s = fmaf(x.x, av[q * 4 + 0], fmaf(x.y, av[q * 4 + 1],
                    fmaf(x.z, av[q * 4 + 2], fmaf(x.w, av[q * 4 + 3], s))));
            }
            s = (s >= 0.f) ? s : 0.2f * s;
            a_self[node * HH + h] = s;
        } else {
            const short8v* p = reinterpret_cast<const short8v*>(&f1b[(size_t)node * DOUTC + h * DHH]);
            const float*  av = &att[h * 32 + DHH];
            union { short8v v; __hip_bfloat16 hh[8]; } pk0, pk1;
            pk0.v = p[0]; pk1.v = p[1];
            #pragma unroll
            for (int q = 0; q < 8; ++q) s = fmaf(__bfloat162float(pk0.hh[q]), av[q], s);
            #pragma unroll
            for (int q = 0; q < 8; ++q) s = fmaf(__bfloat162float(pk1.hh[q]), av[8 + q], s);
            s = (s >= 0.f) ? s : 0.2f * s;
            nodedat[(size_t)node * 16 + h] = s;   // a_neigh half
        }
    } else {
        // bscan: sum HB private slices, exclusive-scan, write gHist/gBase/gCursor
        __shared__ int s[512];
        int v = 0;
        #pragma unroll
        for (int s8 = 0; s8 < HB; ++s8) v += gHistP[s8 * 512 + tid];
        gHist[tid] = v;
        s[tid] = v; __syncthreads();
        for (int off = 1; off < 512; off <<= 1) {
            int add = (tid >= off) ? s[tid - off] : 0;
            __syncthreads();
            s[tid] += add;
            __syncthreads();
        }
        int excl = s[tid] - v;
        gBase[tid] = excl;
        gCursor[tid] = excl;
    }
}

// ---------------- bscatter: edges -> bucket regions ----------------
__global__ __launch_bounds__(256) void bscatter(const int* __restrict__ row, const int* __restrict__ col,
                                                const float* __restrict__ val, int* __restrict__ gCursor,
                                                int2* __restrict__ ebuf, int E) {
    __shared__ int hist[512], base[512], rank[512];
    int tid = threadIdx.x;
    hist[tid] = 0; hist[tid + 256] = 0;
    __syncthreads();
    int e0 = blockIdx.x * EPB;
    #pragma unroll
    for (int k = 0; k < 16; ++k) {
        int e = e0 + k * 256 + tid;
        if (e < E) atomicAdd(&hist[row[e] >> BSHIFT], 1);
    }
    __syncthreads();
    if (hist[tid])       base[tid] = atomicAdd(&gCursor[tid], hist[tid]);
    if (hist[tid + 256]) base[tid + 256] = atomicAdd(&gCursor[tid + 256], hist[tid + 256]);
    rank[tid] = 0; rank[tid + 256] = 0;
    __syncthreads();
    #pragma unroll
    for (int k = 0; k < 16; ++k) {
        int e = e0 + k * 256 + tid;
        if (e < E) {
            int r = row[e];
            int bk = r >> BSHIFT;
            int loc = atomicAdd(&rank[bk], 1);
            int2 pk;
            pk.x = col[e] | ((r & 127) << 16);   // col fits 16 bits (N < 65536)
            pk.y = __float_as_int(val[e]);
            ebuf[base[bk] + loc] = pk;
        }
    }
}

// ---------------- bsort: per-bucket counting sort -> final edges + rowptr ----------------
__global__ __launch_bounds__(256) void bsort(const int2* __restrict__ ebuf, const int* __restrict__ gHist,
                                             const int* __restrict__ gBase, int2* __restrict__ efin,
                                             int* __restrict__ rowptr, int N) {
    __shared__ int2 ent[CAP];
    __shared__ int h0[128], sc[128], rk[128];
    int b = blockIdx.x, tid = threadIdx.x;
    int cnt = gHist[b]; if (cnt > CAP) cnt = CAP;
    int base = gBase[b];
    if (tid < 128) h0[tid] = 0;
    __syncthreads();
    for (int i = tid; i < cnt; i += 256) {
        int2 e = ebuf[base + i];
        ent[i] = e;
        atomicAdd(&h0[(e.x >> 16) & 127], 1);
    }
    __syncthreads();
    if (tid < 128) sc[tid] = h0[tid];
    __syncthreads();
    for (int off = 1; off < 128; off <<= 1) {
        int add = (tid < 128 && tid >= off) ? sc[tid - off] : 0;
        __syncthreads();
        if (tid < 128) sc[tid] += add;
        __syncthreads();
    }
    if (tid < 128) {
        int excl = sc[tid] - h0[tid];
        rk[tid] = excl;
        int grow = b * 128 + tid;
        if (grow <= N) rowptr[grow] = base + excl;   // rowptr[N] = E via last bucket
    }
    __syncthreads();
    for (int i = tid; i < cnt; i += 256) {
        int2 e = ent[i];
        int dst = base + atomicAdd(&rk[(e.x >> 16) & 127], 1);
        efin[dst] = e;
    }
}

// ---------------- edge aggregation + gate + fused dual-norm + output (round-7 form) ----------------
#define UN 8
__global__ __launch_bounds__(128) void edge_kernel(
    const int* __restrict__ rowptr, const int2* __restrict__ ef,
    const __hip_bfloat16* __restrict__ f1b, const __hip_bfloat16* __restrict__ zjb,
    const float* __restrict__ a_self, const float* __restrict__ nodedat,
    const float* __restrict__ fg0, const float* __restrict__ Wg,
    const float* __restrict__ f0, const float* __restrict__ scale, const float* __restrict__ offset,
    float* __restrict__ out) {
    int r = blockIdx.x;
    int t = threadIdx.x;
    int start = rowptr[r], end = rowptr[r + 1];

    __shared__ float lds_z[64];
    __shared__ float lds_n8[8];
    __shared__ float lds_gate[8];

    float accA0 = 0.f, accA1 = 0.f, accZ = -INFINITY, accN8 = 0.f;
    int h = t >> 3;                  // wave0: components (2t,2t+1), h = (2t)>>4 = t>>3
    float asr = 0.f;
    if (t < 64) asr = a_self[r * HH + h];
    int j = t - 64;

    int i = start;
    for (; i + UN <= end; i += UN) {
        int   c[UN]; float v[UN];
        #pragma unroll
        for (int u = 0; u < UN; ++u) {
            int2 eu = ef[i + u];
            c[u] = eu.x & 0xFFFF;
            v[u] = __int_as_float(eu.y);
        }
        if (t < 64) {
            float an[UN];
            #pragma unroll
            for (int u = 0; u < UN; ++u) an[u] = nodedat[(size_t)c[u] * 16 + h];
            __hip_bfloat162 f2[UN];
            #pragma unroll
            for (int u = 0; u < UN; ++u)
                f2[u] = *reinterpret_cast<const __hip_bfloat162*>(&f1b[(size_t)c[u] * DOUTC + 2 * t]);
            #pragma unroll
            for (int u = 0; u < UN; ++u) {
                float w = (asr + an[u]) * v[u];
                accA0 = fmaf(w, __bfloat162float(f2[u].x), accA0);
                accA1 = fmaf(w, __bfloat162float(f2[u].y), accA1);
            }
        } else {
            float z[UN];
            #pragma unroll
            for (int u = 0; u < UN; ++u) z[u] = __bfloat162float(zjb[(size_t)c[u] * DGG + j]);
            #pragma unroll
            for (int u = 0; u < UN; ++u) accZ = fmaxf(accZ, z[u]);
            if (j < 8) {
                float g2[UN];
                #pragma unroll
                for (int u = 0; u < UN; ++u) g2[u] = nodedat[(size_t)c[u] * 16 + 8 + j];
                #pragma unroll
                for (int u = 0; u < UN; ++u) accN8 = fmaf(v[u], g2[u], accN8);
            }
        }
    }
    for (; i < end; ++i) {
        int2 eu = ef[i];
        int   c = eu.x & 0xFFFF;
        float v = __int_as_float(eu.y);
        if (t < 64) {
            float w = (asr + nodedat[(size_t)c * 16 + h]) * v;
            __hip_bfloat162 f2 = *reinterpret_cast<const __hip_bfloat162*>(&f1b[(size_t)c * DOUTC + 2 * t]);
            accA0 = fmaf(w, __bfloat162float(f2.x), accA0);
            accA1 = fmaf(w, __bfloat162float(f2.y), accA1);
        } else {
            accZ = fmaxf(accZ, __bfloat162float(zjb[(size_t)c * DGG + j]));
            if (j < 8) accN8 = fmaf(v, nodedat[(size_t)c * 16 + 8 + j], accN8);
        }
    }

    if (t >= 64) {
        lds_z[j] = (end > start) ? accZ : 0.f;  // isolated node -> 0
        if (j < 8) lds_n8[j] = accN8;
    }
    __syncthreads();

    if (t < 8) {   // gate[h] = fg0 + zmax . Wg[128:192] + nm8
        float g = fg0[r * HH + t] + lds_n8[t];
        #pragma unroll
        for (int k = 0; k < 64; ++k) g = fmaf(lds_z[k], Wg[(128 + k) * HH + t], g);
        lds_gate[t] = g;
    }
    __syncthreads();

    if (t < 64) {
        float gh  = lds_gate[h];
        float h1x = accA0 * gh, h1y = accA1 * gh;
        float2 f0v = *reinterpret_cast<const float2*>(&f0[r * DOUTC + 2 * t]);
        float s0  = f0v.x + f0v.y;
        float s0q = f0v.x * f0v.x + f0v.y * f0v.y;
        float s1  = h1x + h1y;
        float s1q = h1x * h1x + h1y * h1y;
        #pragma unroll
        for (int off = 32; off > 0; off >>= 1) {
            s0  += __shfl_xor(s0,  off);
            s0q += __shfl_xor(s0q, off);
            s1  += __shfl_xor(s1,  off);
            s1q += __shfl_xor(s1q, off);
        }
        float mu0  = s0 * (1.f / 128.f), mu1 = s1 * (1.f / 128.f);
        float rs0  = rsqrtf(s0q * (1.f / 128.f) - mu0 * mu0 + 1e-9f);
        float rs1  = rsqrtf(s1q * (1.f / 128.f) - mu1 * mu1 + 1e-9f);
        float2 sc0 = *reinterpret_cast<const float2*>(&scale[2 * t]);
        float2 sc1 = *reinterpret_cast<const float2*>(&scale[128 + 2 * t]);
        float2 of0 = *reinterpret_cast<const float2*>(&offset[2 * t]);
        float2 of1 = *reinterpret_cast<const float2*>(&offset[128 + 2 * t]);
        float2 o2;
        o2.x = (f0v.x - mu0) * sc0.x * rs0 + of0.x + (h1x - mu1) * sc1.x * rs1 + of1.x;
        o2.y = (f0v.y - mu0) * sc0.y * rs0 + of0.y + (h1y - mu1) * sc1.y * rs1 + of1.y;
        *reinterpret_cast<float2*>(&out[r * DOUTC + 2 * t]) = o2;
    }
}

// ---------------- launch ----------------
extern "C" void kernel_launch(void* const* d_in, const int* in_sizes, int n_in,
                              void* d_out, int out_size, void* d_ws, size_t ws_size,
                              hipStream_t stream) {
    const int*   row  = (const int*)  d_in[0];
    const int*   col  = (const int*)  d_in[1];
    const float* val  = (const float*)d_in[2];
    const float* feat = (const float*)d_in[3];
    const float* W    = (const float*)d_in[4];
    const float* b    = (const float*)d_in[5];
    const float* att  = (const float*)d_in[6];
    const float* offs = (const float*)d_in[7];
    const float* scal = (const float*)d_in[8];
    const float* Wg   = (const float*)d_in[9];
    const float* Wpg  = (const float*)d_in[10];
    float* out = (float*)d_out;

    const int E = in_sizes[0];
    const int N = in_sizes[3] / DIN;
    const int NBUCK = (N + 127) >> BSHIFT;       // 391 for N=50000
    const int NEBLK = (E + EPB - 1) / EPB;       // 391 for E=1.6M

    char* ws = (char*)d_ws;
    size_t off = 0;
    auto alloc = [&](size_t bytes) { size_t o = off; off = (off + bytes + 255) & ~(size_t)255; return o; };

    __hip_bfloat16* featb = (__hip_bfloat16*)(ws + alloc((size_t)N * DIN * 2));
    __hip_bfloat16* Btb   = (__hip_bfloat16*)(ws + alloc((size_t)NC2 * DIN * 2));
    float* biasv   = (float*)(ws + alloc(NC2 * 4));
    float* f0      = (float*)(ws + alloc((size_t)N * DOUTC * 4));
    __hip_bfloat16* f1b = (__hip_bfloat16*)(ws + alloc((size_t)N * DOUTC * 2));
    __hip_bfloat16* zjb = (__hip_bfloat16*)(ws + alloc((size_t)N * DGG * 2));
    float* a_self  = (float*)(ws + alloc((size_t)N * HH * 4));
    float* nodedat = (float*)(ws + alloc((size_t)N * 16 * 4));   // [a_neigh(8) | fg2(8)] per node
    float* fg0     = (float*)(ws + alloc((size_t)N * HH * 4));
    int*   rowptr  = (int*)  (ws + alloc((size_t)(N + 1) * 4));
    int*   gHistP  = (int*)  (ws + alloc((size_t)HB * 512 * 4));
    int*   gHist   = (int*)  (ws + alloc(512 * 4));
    int*   gBase   = (int*)  (ws + alloc(512 * 4));
    int*   gCursor = (int*)  (ws + alloc(512 * 4));
    int2*  ebuf    = (int2*) (ws + alloc((size_t)E * 8));
    int2*  efin    = (int2*) (ws + alloc((size_t)E * 8));

    // 1. setup: feat->bf16 | pack swizzled B^T | bucket histogram slices
    const int total8 = N * DIN / 8;
    const int cvtB = (total8 + 255) / 256;
    const int prepB = (NC2 * DIN + 255) / 256;
    const int EH = (E + HB - 1) / HB;
    setup_kernel<<<cvtB + prepB + HB, 256, 0, stream>>>(
        feat, W, b, Wg, Wpg, row, featb, Btb, biasv, gHistP, total8, cvtB, prepB, E, EH);
    // 2. dense MFMA GEMM v2 + (256,1)
    dense_mfma<<<(N + 127) / 128, 256, 0, stream>>>(featb, Btb, biasv, f0, f1b, zjb, fg0, nodedat, N);
    // 3. mid: attention scalars | bucket scan
    const int attnB = (N * 16 + 511) / 512;
    mid_kernel<<<attnB + 1, 512, 0, stream>>>(f0, f1b, att, a_self, nodedat,
                                              gHistP, gHist, gBase, gCursor, N, attnB);
    // 4. bucketed counting sort
    bscatter<<<NEBLK, 256, 0, stream>>>(row, col, val, gCursor, ebuf, E);
    bsort<<<NBUCK, 256, 0, stream>>>(ebuf, gHist, gBase, efin, rowptr, N);
    // 5. per-node aggregation + gate + norm + output (grid = N, round-7 form)
    edge_kernel<<<N, 128, 0, stream>>>(rowptr, efin, f1b, zjb, a_self, nodedat,
                                       fg0, Wg, f0, scal, offs, out);
}